// Round 9
// baseline (1402.859 us; speedup 1.0000x reference)
//
#include <hip/hip_runtime.h>
#include <math.h>

#define Bsz 512
#define Tsz 512
#define Fin 32
#define Hd 64
#define NG 256            // 4*Hd gate rows
#define PH 8              // steps per phase (barrier period)
#define NPH (Tsz / PH)    // 64 phases

typedef float v2f __attribute__((ext_vector_type(2)));

__device__ __forceinline__ float fsig(float x) {
    return __builtin_amdgcn_rcpf(1.0f + __expf(-x));
}
__device__ __forceinline__ float ftanh(float x) {
    return fmaf(2.0f, __builtin_amdgcn_rcpf(1.0f + __expf(-2.0f * x)), -1.0f);
}

// Pin float4 components into arch VGPRs (blocks AGPR parking; round-3 proven).
#define PIN4(v4) \
    asm volatile("" : "+v"((v4).x), "+v"((v4).y), "+v"((v4).z), "+v"((v4).w))

// ============================================================================
// R9: producer-consumer wave pair per batch row; barrier every PH=8 steps.
//
// Wave 1 (producer): lane l holds Wih rows {q*64+l} in VGPR; computes the
//   input projection xg[t][r] = bias_r + X[t]·Wih[r] for 8 steps ahead into
//   a double-buffered LDS ring (no recurrence -> can run ahead).
// Wave 0 (consumer): lane l holds Whh rows {q*64+l}; per step reads its 4
//   gate pre-activations from the ring (conflict-free b32), adds the h-dot
//   from the wave-private hrow broadcast (in-order DS pipe: same-wave
//   write->read needs NO barrier - the R3-proven pattern), applies the
//   activations, updates c,h, writes hrow.
//
// The 512-step recurrence thus contains ZERO per-step barriers; the two
// waves sync only at 8-step phase boundaries (65 barriers total).
// Both branches share one wreg[4][16] array (producer: Wih, consumer: Whh),
// so kernel VGPR ~= 290 -> 1 wave/SIMD; 2-wave blocks, grid 512 = 2
// blocks/CU = 4 waves on 4 SIMDs. Workspace: h1 only (67.1 MB, known-safe).
// ============================================================================
template <int K, bool LAST>
__global__ __launch_bounds__(128, 1)
void lstm_pc(const float* __restrict__ X,        // [B,T,K] layer input
             const float4* __restrict__ Wih4,    // [4H][K/4]
             const float4* __restrict__ Whh4,    // [4H][Hd/4]
             const float* __restrict__ bih,
             const float* __restrict__ bhh,
             float* __restrict__ hout,           // !LAST: h1 out [B,T,Hd]
             const float* __restrict__ fcW,      // LAST only
             const float* __restrict__ fcb,
             float* __restrict__ out)
{
    __shared__ __align__(16) float ring[2][PH][NG];    // 16 KB gate ring
    __shared__ __align__(16) float xstage[2][PH * K];  // x rows (dbuf)
    __shared__ __align__(16) float hrow[Hd];           // consumer-private h

    const int tid = threadIdx.x;
    const int l   = tid & 63;
    const int wv  = tid >> 6;      // 0 = consumer (recurrence), 1 = producer
    const int b   = blockIdx.x;

    float4 wreg[4][16];            // producer: Wih rows; consumer: Whh rows
    float  bias[4];
    float  c = 0.0f, hcur = 0.0f;

    const float4* xb4 = (const float4*)(X + (size_t)b * Tsz * K);
    constexpr int NF4 = PH * K / 4;   // float4s per phase (64 or 128)
    constexpr int LPT = NF4 / 64;     // float4 loads per lane per phase

    if (wv == 1) {
#pragma unroll
        for (int q = 0; q < 4; ++q) {
#pragma unroll
            for (int j = 0; j < K / 4; ++j)
                wreg[q][j] = Wih4[(q * Hd + l) * (K / 4) + j];
            bias[q] = bih[q * Hd + l] + bhh[q * Hd + l];
        }
        // stage phase 0's x rows
#pragma unroll
        for (int i = 0; i < LPT; ++i)
            ((float4*)xstage[0])[i * 64 + l] = xb4[i * 64 + l];
    } else {
#pragma unroll
        for (int q = 0; q < 4; ++q)
#pragma unroll
            for (int j = 0; j < 16; ++j)
                wreg[q][j] = Whh4[(q * Hd + l) * 16 + j];
        hrow[l] = 0.0f;            // same-wave in-order: visible to own reads
    }

    float* hol = nullptr;
    if constexpr (!LAST) hol = hout + (size_t)b * Tsz * Hd + l;

    for (int ph = 0; ph <= NPH; ++ph) {
        if (wv == 1) {
            if (ph < NPH) {
#pragma unroll
                for (int q = 0; q < 4; ++q)
#pragma unroll
                    for (int j = 0; j < K / 4; ++j) PIN4(wreg[q][j]);
                // prefetch next phase's x rows into regs (hides HBM/L2 lat)
                float4 pref[LPT];
                const bool hasNext = (ph + 1 < NPH);
                if (hasNext) {
#pragma unroll
                    for (int i = 0; i < LPT; ++i)
                        pref[i] = xb4[(size_t)(ph + 1) * NF4 + i * 64 + l];
                }
                // compute 8 steps of gate pre-activations from xstage[ph&1]
                float* rg = &ring[ph & 1][0][0];
#pragma unroll 1
                for (int tt = 0; tt < PH; ++tt) {
                    const float4* xr = (const float4*)&xstage[ph & 1][tt * K];
                    v2f a0[4], a1[4];
#pragma unroll
                    for (int q = 0; q < 4; ++q) {
                        a0[q].x = bias[q]; a0[q].y = 0.0f;
                        a1[q].x = 0.0f;    a1[q].y = 0.0f;
                    }
#pragma unroll
                    for (int k = 0; k < K / 4; ++k) {
                        float4 xv = xr[k];
                        v2f b0 = {xv.x, xv.y}, b1 = {xv.z, xv.w};
#pragma unroll
                        for (int q = 0; q < 4; ++q) {
                            v2f w0 = {wreg[q][k].x, wreg[q][k].y};
                            v2f w1 = {wreg[q][k].z, wreg[q][k].w};
                            a0[q] = __builtin_elementwise_fma(b0, w0, a0[q]);
                            a1[q] = __builtin_elementwise_fma(b1, w1, a1[q]);
                        }
                    }
#pragma unroll
                    for (int q = 0; q < 4; ++q)
                        rg[tt * NG + q * Hd + l] =
                            (a0[q].x + a0[q].y) + (a1[q].x + a1[q].y);
                }
                // write prefetched rows to the other stage buffer
                if (hasNext) {
#pragma unroll
                    for (int i = 0; i < LPT; ++i)
                        ((float4*)xstage[(ph + 1) & 1])[i * 64 + l] = pref[i];
                }
            }
        } else if (ph >= 1) {
#pragma unroll
            for (int q = 0; q < 4; ++q)
#pragma unroll
                for (int j = 0; j < 16; ++j) PIN4(wreg[q][j]);
            const int t0 = (ph - 1) * PH;
            const float* rg = &ring[(ph - 1) & 1][0][0];
#pragma unroll 1
            for (int tt = 0; tt < PH; ++tt) {
                v2f a0[4], a1[4];
#pragma unroll
                for (int q = 0; q < 4; ++q) {
                    a0[q].x = rg[tt * NG + q * Hd + l]; a0[q].y = 0.0f;
                    a1[q].x = 0.0f;                     a1[q].y = 0.0f;
                }
                const float4* hp = (const float4*)hrow;  // broadcast reads
#pragma unroll
                for (int k = 0; k < 16; ++k) {
                    float4 hv = hp[k];
                    v2f b0 = {hv.x, hv.y}, b1 = {hv.z, hv.w};
#pragma unroll
                    for (int q = 0; q < 4; ++q) {
                        v2f w0 = {wreg[q][k].x, wreg[q][k].y};
                        v2f w1 = {wreg[q][k].z, wreg[q][k].w};
                        a0[q] = __builtin_elementwise_fma(b0, w0, a0[q]);
                        a1[q] = __builtin_elementwise_fma(b1, w1, a1[q]);
                    }
                }
                float ai = (a0[0].x + a0[0].y) + (a1[0].x + a1[0].y);
                float af = (a0[1].x + a0[1].y) + (a1[1].x + a1[1].y);
                float ag = (a0[2].x + a0[2].y) + (a1[2].x + a1[2].y);
                float ao = (a0[3].x + a0[3].y) + (a1[3].x + a1[3].y);
                float gi = fsig(ai), gf = fsig(af);
                float gg = ftanh(ag), go = fsig(ao);
                c    = fmaf(gf, c, gi * gg);
                hcur = go * ftanh(c);
                hrow[l] = hcur;                      // in-order, own wave
                if constexpr (!LAST) hol[(size_t)(t0 + tt) * Hd] = hcur;
            }
        }
        __syncthreads();   // phase boundary: ring[ph&1] handoff
    }

    if (LAST && wv == 0) {
        // fused FC: lane l holds h2[b, T-1, l]
        float psum = hcur * fcW[l];
#pragma unroll
        for (int off = 32; off > 0; off >>= 1)
            psum += __shfl_down(psum, off);
        if (l == 0) out[b] = psum + fcb[0];
    }
}

extern "C" void kernel_launch(void* const* d_in, const int* in_sizes, int n_in,
                              void* d_out, int out_size, void* d_ws, size_t ws_size,
                              hipStream_t stream)
{
    const float* x    = (const float*)d_in[0];
    const float* Wih0 = (const float*)d_in[1];
    const float* Whh0 = (const float*)d_in[2];
    const float* bih0 = (const float*)d_in[3];
    const float* bhh0 = (const float*)d_in[4];
    const float* Wih1 = (const float*)d_in[5];
    const float* Whh1 = (const float*)d_in[6];
    const float* bih1 = (const float*)d_in[7];
    const float* bhh1 = (const float*)d_in[8];
    const float* fcW  = (const float*)d_in[9];
    const float* fcb  = (const float*)d_in[10];
    float* out = (float*)d_out;
    float* h1  = (float*)d_ws;   // B*T*H fp32 = 67.1 MB (known to fit)

    lstm_pc<Fin, false><<<dim3(Bsz), dim3(128), 0, stream>>>(
        x, (const float4*)Wih0, (const float4*)Whh0, bih0, bhh0, h1,
        nullptr, nullptr, nullptr);
    lstm_pc<Hd, true><<<dim3(Bsz), dim3(128), 0, stream>>>(
        h1, (const float4*)Wih1, (const float4*)Whh1, bih1, bhh1, nullptr,
        fcW, fcb, out);
}